// Round 12
// baseline (378.288 us; speedup 1.0000x reference)
//
#include <hip/hip_runtime.h>

#define DN  256   // DAGs
#define NN  1024  // nodes per DAG
#define PP  8     // max predecessors
#define LL  104   // feature dim
#define CLS 500   // classes
#define BT  512   // threads per block (8 waves)
#define TMAX 64   // node tile per level pass
#define KP  232   // padded K stride in bf16 elems
#define NG  26    // float4 feature groups (104/4)

typedef __attribute__((ext_vector_type(8))) short short8;
typedef __attribute__((ext_vector_type(4))) short short4v;
typedef __attribute__((ext_vector_type(4))) float f32x4;

#define MFMA(a, b, c) __builtin_amdgcn_mfma_f32_16x16x32_bf16((a), (b), (c), 0, 0, 0)

__device__ __forceinline__ void split_bf16(float x, unsigned short& h, unsigned short& l) {
    unsigned u = __float_as_uint(x);
    h = (unsigned short)(u >> 16);
    float hf = __uint_as_float(u & 0xFFFF0000u);
    l = (unsigned short)(__float_as_uint(x - hf) >> 16);
}

// softmax over preds + split + x-store; ft arrives PRE-SPLIT (fth/ftl)
__device__ __forceinline__ void sm_store2(int ni, int lg, int vmask,
    const float4 pv[PP], short4v fth, short4v ftl, const float* s_attn2,
    unsigned short (*xh)[KP], unsigned short (*xl)[KP])
{
    float4 aw = *(const float4*)&s_attn2[lg * 4];
    float awv[4] = {aw.x, aw.y, aw.z, aw.w};
    unsigned short oh[4], ol[4];
    #pragma unroll
    for (int f = 0; f < 4; ++f) {
        float den = 0.f, num = 0.f;
        #pragma unroll
        for (int q = 0; q < PP; ++q) {
            float pvq = ((const float*)&pv[q])[f];
            float e2 = exp2f(awv[f] * pvq);     // shift-invariant; bounded values
            e2 = ((vmask >> q) & 1) ? e2 : 0.f;
            den += e2;
            num = fmaf(e2, pvq, num);
        }
        float agg = __fdividef(num, den);
        split_bf16(agg, oh[f], ol[f]);
    }
    *(short4v*)&xh[ni][lg*4] = (short4v){(short)oh[0], (short)oh[1], (short)oh[2], (short)oh[3]};
    *(short4v*)&xl[ni][lg*4] = (short4v){(short)ol[0], (short)ol[1], (short)ol[2], (short)ol[3]};
    *(short4v*)&xh[ni][LL + lg*4] = fth;
    *(short4v*)&xl[ni][LL + lg*4] = ftl;
}

// One block per DAG, 8 waves. Level-scheduled split-bf16 MFMA GEMM per level.
// Graph precomputed in sorted-position space (ppos_lds); fresh preds read from
// out_lds; old preds prefetched during prior phase B; out_d global stores are
// deferred to the NEXT tile's phase A (store-ack off the barrier chain).
__global__ __launch_bounds__(BT, 2) void dag_level_kernel(
    const float* __restrict__ atom,      // [DN][NN][LL]
    const int*   __restrict__ pred,      // [DN][NN][PP]
    const float* __restrict__ W_single,  // [LL][LL]
    const float* __restrict__ b_single,  // [LL]
    const float* __restrict__ W_merge,   // [LL][2*LL]
    const float* __restrict__ b_merge,   // [LL]
    const float* __restrict__ attn_w,    // [LL]
    float* __restrict__ out_all,         // ws: [DN][NN][LL]
    float* __restrict__ last_buf)        // ws: [DN][LL]
{
    __shared__ __align__(16) unsigned short x_hi[TMAX][KP];   // 29 KB
    __shared__ __align__(16) unsigned short x_lo[TMAX][KP];   // 29 KB
    __shared__ __align__(16) unsigned short ppos_lds[NN][PP]; // 16 KB pred positions
    __shared__ __align__(16) float out_lds[TMAX][LL];         // 26 KB prev-tile outputs
    __shared__ int   lvl[NN];                                 // 4 KB
    __shared__ int   cnt[NN];                                 // 4 KB
    __shared__ unsigned short order[NN];                      // 2 KB pos -> node
    __shared__ unsigned short pos_lds[NN];                    // 2 KB node -> pos
    __shared__ __align__(16) float s_attn2[LL];               // attn_w * log2(e)
    __shared__ float s_bm[LL];
    __shared__ int   csum[64];
    __shared__ int   s_flag, s_maxlvl;

    const int d    = blockIdx.x;
    const int tid  = threadIdx.x;
    const int wid  = tid >> 6;
    const int lane = tid & 63;

    const float* atom_d = atom + (size_t)d * NN * LL;
    const int*   pred_d = pred + (size_t)d * NN * PP;
    float*       out_d  = out_all + (size_t)d * NN * LL;

    // ---- W_merge fragments -> registers. Wave w owns nt = min(w,6) ----
    short8 wh[7], wl[7];
    {
        const int r = min(wid, 6)*16 + (lane & 15);
        #pragma unroll
        for (int kt = 0; kt < 7; ++kt) {
            const int k0 = kt*32 + (lane >> 4)*8;
            short8 hh, lo8;
            #pragma unroll
            for (int j = 0; j < 8; ++j) {
                float v = (r < LL && (k0 + j) < 2*LL) ? W_merge[r*2*LL + k0 + j] : 0.f;
                unsigned short a, b;
                split_bf16(v, a, b);
                hh[j] = (short)a; lo8[j] = (short)b;
            }
            wh[kt] = hh; wl[kt] = lo8;
        }
    }

    // ---- init ----
    for (int idx = tid; idx < TMAX * (KP - 2*LL); idx += BT) {
        int rr = idx / (KP - 2*LL), cc = 2*LL + (idx - rr*(KP - 2*LL));
        x_hi[rr][cc] = 0; x_lo[rr][cc] = 0;
    }
    if (tid < LL) { s_attn2[tid] = attn_w[tid] * 1.44269504f; s_bm[tid] = b_merge[tid]; }
    if (tid == 0) { s_flag = 0; s_maxlvl = 0; }
    lvl[tid] = 0; lvl[tid + BT] = 0;

    // ---- preds of my 2 nodes -> registers (global, coalesced) ----
    int mypA[PP], mypB[PP];
    {
        const int4* p4 = (const int4*)(pred_d + tid * PP);
        int4 a = p4[0], b = p4[1];
        mypA[0]=a.x; mypA[1]=a.y; mypA[2]=a.z; mypA[3]=a.w;
        mypA[4]=b.x; mypA[5]=b.y; mypA[6]=b.z; mypA[7]=b.w;
        const int4* q4 = (const int4*)(pred_d + (tid + BT) * PP);
        int4 c = q4[0], e = q4[1];
        mypB[0]=c.x; mypB[1]=c.y; mypB[2]=c.z; mypB[3]=c.w;
        mypB[4]=e.x; mypB[5]=e.y; mypB[6]=e.z; mypB[7]=e.w;
    }
    __syncthreads();

    // ---- 1. level relaxation: 2 nodes/thread, double monotone sweep ----
    for (int it = 1; it <= NN; ++it) {
        bool ch = false;
        #pragma unroll
        for (int rep = 0; rep < 2; ++rep) {
            int mxA = -1, mxB = -1;
            #pragma unroll
            for (int q = 0; q < PP; ++q) {
                if (mypA[q] >= 0) mxA = max(mxA, lvl[mypA[q]]);
                if (mypB[q] >= 0) mxB = max(mxB, lvl[mypB[q]]);
            }
            if (mxA + 1 != lvl[tid])      { lvl[tid]      = mxA + 1; ch = true; }
            if (mxB + 1 != lvl[tid + BT]) { lvl[tid + BT] = mxB + 1; ch = true; }
        }
        if (ch) s_flag = it;
        __syncthreads();
        int f = s_flag;
        __syncthreads();
        if (f != it) break;
    }
    atomicMax(&s_maxlvl, max(lvl[tid], lvl[tid + BT]));

    // ---- 2. counting sort by level (order + pos) ----
    cnt[tid] = 0; cnt[tid + BT] = 0;
    __syncthreads();
    atomicAdd(&cnt[lvl[tid]], 1);
    atomicAdd(&cnt[lvl[tid + BT]], 1);
    __syncthreads();
    if (tid < 64) { int s = 0; for (int i = 0; i < 16; ++i) s += cnt[tid*16 + i]; csum[tid] = s; }
    __syncthreads();
    if (tid == 0) { int run = 0; for (int t = 0; t < 64; ++t) { int c = csum[t]; csum[t] = run; run += c; } }
    __syncthreads();
    if (tid < 64) {
        int run = csum[tid];
        for (int i = 0; i < 16; ++i) { int c = cnt[tid*16 + i]; cnt[tid*16 + i] = run; run += c; }
    }
    __syncthreads();
    {
        int pos = atomicAdd(&cnt[lvl[tid]], 1);
        order[pos] = (unsigned short)tid;        pos_lds[tid] = (unsigned short)pos;
        pos = atomicAdd(&cnt[lvl[tid + BT]], 1);
        order[pos] = (unsigned short)(tid + BT); pos_lds[tid + BT] = (unsigned short)pos;
    }
    __syncthreads();

    // ---- 2b. build position-space graph: ppos_lds[pos][q] (0xFFFF = none) ----
    {
        unsigned short tA[PP], tB[PP];
        #pragma unroll
        for (int q = 0; q < PP; ++q) {
            tA[q] = (mypA[q] < 0) ? (unsigned short)0xFFFFu : pos_lds[mypA[q]];
            tB[q] = (mypB[q] < 0) ? (unsigned short)0xFFFFu : pos_lds[mypB[q]];
        }
        int pA = pos_lds[tid], pB = pos_lds[tid + BT];
        *(short4v*)&ppos_lds[pA][0] = (short4v){(short)tA[0],(short)tA[1],(short)tA[2],(short)tA[3]};
        *(short4v*)&ppos_lds[pA][4] = (short4v){(short)tA[4],(short)tA[5],(short)tA[6],(short)tA[7]};
        *(short4v*)&ppos_lds[pB][0] = (short4v){(short)tB[0],(short)tB[1],(short)tB[2],(short)tB[3]};
        *(short4v*)&ppos_lds[pB][4] = (short4v){(short)tB[4],(short)tB[5],(short)tB[6],(short)tB[7]};
    }

    // ---- 3. level-0 (root) nodes via W_single; write out_d + out_lds ----
    __syncthreads();
    {
        int nroots = cnt[0];
        for (int task = tid; task < nroots * LL; task += BT) {
            int ni = task / LL, r = task - ni * LL;
            int n = order[ni];
            float acc = b_single[r];
            const float* feat = atom_d + n * LL;
            const float* wr = W_single + r * LL;
            #pragma unroll 8
            for (int l = 0; l < LL; ++l) acc = fmaf(wr[l], feat[l], acc);
            float v = fmaxf(acc, 0.f);
            out_d[n * LL + r] = v;
            if (ni < TMAX) out_lds[ni][r] = v;
            if (n == NN - 1) last_buf[d * LL + r] = v;
        }
    }
    __syncthreads();

    const int maxlvl = s_maxlvl;

    // ---- prefetch state for round-1 task (tid) of the NEXT tile ----
    float4  pf_po[PP];                    // old pred rows (global, final)
    short4v pf_fth = {0,0,0,0}, pf_ftl = {0,0,0,0};  // pre-split feat

    // Issue gathers for next tile [NT0,NT0+NTC); CT0 = current tile start.
    // Preds with pos >= CT0 are "fresh-for-next" (come via out_lds later).
#define PREFETCH(NT0, NTC, CT0) do {                                           \
        if (tid < (NTC) * NG) {                                                \
            int ni_ = tid / NG, lg_ = tid - ni_ * NG;                          \
            int n_ = order[(NT0) + ni_];                                       \
            float4 ft_ = *(const float4*)&atom_d[n_ * LL + lg_ * 4];           \
            unsigned short h0_,h1_,h2_,h3_,l0_,l1_,l2_,l3_;                    \
            split_bf16(ft_.x, h0_, l0_); split_bf16(ft_.y, h1_, l1_);          \
            split_bf16(ft_.z, h2_, l2_); split_bf16(ft_.w, h3_, l3_);          \
            pf_fth = (short4v){(short)h0_,(short)h1_,(short)h2_,(short)h3_};   \
            pf_ftl = (short4v){(short)l0_,(short)l1_,(short)l2_,(short)l3_};   \
            short8 pps_ = *(const short8*)&ppos_lds[(NT0) + ni_][0];           \
            _Pragma("unroll")                                                  \
            for (int q_ = 0; q_ < PP; ++q_) {                                  \
                int pp_ = (unsigned short)pps_[q_];                            \
                bool old_ = (pp_ != 0xFFFF) && (pp_ < (CT0));                  \
                int row_ = old_ ? (int)order[pp_] : 0;                         \
                pf_po[q_] = *(const float4*)&out_d[row_ * LL + lg_ * 4];       \
            }                                                                  \
        }                                                                      \
    } while (0)

    int pt0 = 0, ptc = cnt[0];   // "previous tile" = level-0 tile

    if (maxlvl >= 1) {
        int s1 = cnt[0];
        PREFETCH(s1, min(TMAX, cnt[1] - s1), 0);
    }

    // ---- 4. main level loop ----
    for (int L = 1; L <= maxlvl; ++L) {
        const int s = cnt[L - 1], e = cnt[L];
        for (int t0 = s; t0 < e; t0 += TMAX) {
            const int tc = min(TMAX, e - t0);
            const int ntask = tc * NG;
            const int pcopy = ptc * NG;
            const bool has_task = tid < ntask;

            // ---------- phase A ----------
            // deferred global store of PREVIOUS tile (idle threads first)
            if (!has_task) {
                for (int ct = (BT - 1) - tid; ct < pcopy; ct += BT) {
                    int ci = ct / NG, lg = ct - ci * NG;
                    int n = order[pt0 + ci];
                    *(float4*)&out_d[n * LL + lg * 4] = *(const float4*)&out_lds[ci][lg * 4];
                }
            }
            // round 1: chain is LDS + VALU only (pf regs + out_lds + ppos)
            if (has_task) {
                int ni = tid / NG, lg = tid - ni * NG;
                short8 pps = *(const short8*)&ppos_lds[t0 + ni][0];
                float4 pv[PP]; int vmask = 0;
                #pragma unroll
                for (int q = 0; q < PP; ++q) {
                    int pp = (unsigned short)pps[q];
                    bool valid = pp != 0xFFFF;
                    bool fresh = valid && pp >= pt0;
                    vmask |= (valid ? 1 : 0) << q;
                    int slot = fresh ? (pp - pt0) : 0;
                    float4 lv = *(const float4*)&out_lds[slot][lg * 4];
                    pv[q] = fresh ? lv : pf_po[q];
                }
                sm_store2(ni, lg, vmask, pv, pf_fth, pf_ftl, s_attn2, x_hi, x_lo);
                for (int ct = (BT - 1) - tid; ct < pcopy; ct += BT) {
                    int ci = ct / NG, lg2 = ct - ci * NG;
                    int n = order[pt0 + ci];
                    *(float4*)&out_d[n * LL + lg2 * 4] = *(const float4*)&out_lds[ci][lg2 * 4];
                }
            }
            // rounds 2+ (tc > 19 only): global path with out_lds for fresh
            for (int task = tid + BT; task < ntask; task += BT) {
                int ni = task / NG, lg = task - ni * NG;
                short8 pps = *(const short8*)&ppos_lds[t0 + ni][0];
                int vmask = 0; int slotv[PP]; float4 gv[PP];
                #pragma unroll
                for (int q = 0; q < PP; ++q) {
                    int pp = (unsigned short)pps[q];
                    bool valid = pp != 0xFFFF;
                    bool fresh = valid && pp >= pt0;
                    vmask |= (valid ? 1 : 0) << q;
                    slotv[q] = fresh ? (pp - pt0) : -1;
                    int row = (valid && !fresh) ? (int)order[pp] : 0;
                    gv[q] = *(const float4*)&out_d[row * LL + lg * 4];
                }
                float4 pv[PP];
                #pragma unroll
                for (int q = 0; q < PP; ++q) {
                    int sl = slotv[q] >= 0 ? slotv[q] : 0;
                    float4 lv = *(const float4*)&out_lds[sl][lg * 4];
                    pv[q] = (slotv[q] >= 0) ? lv : gv[q];
                }
                int n = order[t0 + ni];
                float4 ft = *(const float4*)&atom_d[n * LL + lg * 4];
                unsigned short h0,h1,h2,h3,l0,l1,l2,l3;
                split_bf16(ft.x, h0, l0); split_bf16(ft.y, h1, l1);
                split_bf16(ft.z, h2, l2); split_bf16(ft.w, h3, l3);
                short4v fth = (short4v){(short)h0,(short)h1,(short)h2,(short)h3};
                short4v ftl = (short4v){(short)l0,(short)l1,(short)l2,(short)l3};
                sm_store2(ni, lg, vmask, pv, fth, ftl, s_attn2, x_hi, x_lo);
            }
            __syncthreads();

            // ---------- phase B ----------
            // issue next tile's prefetch first (hidden under MFMA)
            {
                int nt0 = 0, ntc = 0;
                if (t0 + TMAX < e)        { nt0 = t0 + TMAX; ntc = min(TMAX, e - nt0); }
                else if (L + 1 <= maxlvl) { nt0 = e;         ntc = min(TMAX, cnt[L + 1] - e); }
                PREFETCH(nt0, ntc, t0);
            }

            if (wid < 7) {
                const int mts = (tc + 15) >> 4;
                const int kg = (lane >> 4) * 8;
                const int r0 = wid*16 + (lane & 15);
                for (int mt = 0; mt < mts; ++mt) {
                    const int row_a = mt*16 + (lane & 15);
                    f32x4 a0 = {0.f,0.f,0.f,0.f}, b0 = {0.f,0.f,0.f,0.f}, c0 = {0.f,0.f,0.f,0.f};
                    #pragma unroll
                    for (int kt = 0; kt < 7; ++kt) {
                        const int k0 = kt*32 + kg;
                        short8 ah = *(const short8*)&x_hi[row_a][k0];
                        short8 al = *(const short8*)&x_lo[row_a][k0];
                        a0 = MFMA(ah, wh[kt], a0);
                        b0 = MFMA(ah, wl[kt], b0);
                        c0 = MFMA(al, wh[kt], c0);
                    }
                    f32x4 acc = a0 + b0 + c0;
                    if (r0 < LL) {
                        #pragma unroll
                        for (int j = 0; j < 4; ++j) {
                            int ni = mt*16 + (lane >> 4)*4 + j;
                            if (ni < tc) {
                                float v = fmaxf(acc[j] + s_bm[r0], 0.f);
                                out_lds[ni][r0] = v;              // LDS only
                                int n = order[t0 + ni];
                                if (n == NN - 1) last_buf[d*LL + r0] = v;
                            }
                        }
                    }
                }
            }
            __syncthreads();  // x/out_lds reuse for next tile
            pt0 = t0; ptc = tc;
        }
    }
    // final tile's rows: only node NN-1 matters downstream (last_buf, done)
#undef PREFETCH
}

// Cross-DAG softmax pool + final classifier. Single block.
__global__ __launch_bounds__(256) void final_pool_kernel(
    const float* __restrict__ last_buf,  // [DN][LL]
    const float* __restrict__ dag_w,     // [LL]
    const float* __restrict__ W_final,   // [CLS][LL]
    const float* __restrict__ b_final,   // [CLS]
    float* __restrict__ out)             // [CLS]
{
    __shared__ float s_pooled[LL];
    const int tid = threadIdx.x;

    if (tid < LL) {
        float dw = dag_w[tid];
        float m = -1e30f;
        #pragma unroll 8
        for (int dd = 0; dd < DN; ++dd)
            m = fmaxf(m, dw * last_buf[dd * LL + tid]);
        float den = 0.f, num = 0.f;
        #pragma unroll 8
        for (int dd = 0; dd < DN; ++dd) {
            float v = last_buf[dd * LL + tid];
            float e = __expf(dw * v - m);
            den += e;
            num = fmaf(e, v, num);
        }
        s_pooled[tid] = num / den;
    }
    __syncthreads();

    for (int c = tid; c < CLS; c += 256) {
        float acc = b_final[c];
        const float* wr = W_final + c * LL;
        #pragma unroll 8
        for (int l = 0; l < LL; ++l) acc = fmaf(wr[l], s_pooled[l], acc);
        out[c] = acc;
    }
}

extern "C" void kernel_launch(void* const* d_in, const int* in_sizes, int n_in,
                              void* d_out, int out_size, void* d_ws, size_t ws_size,
                              hipStream_t stream) {
    const float* atom     = (const float*)d_in[0];
    const int*   pred     = (const int*)  d_in[1];
    const float* W_single = (const float*)d_in[2];
    const float* b_single = (const float*)d_in[3];
    const float* W_merge  = (const float*)d_in[4];
    const float* b_merge  = (const float*)d_in[5];
    const float* attn_w   = (const float*)d_in[6];
    const float* dag_w    = (const float*)d_in[7];
    const float* W_final  = (const float*)d_in[8];
    const float* b_final  = (const float*)d_in[9];
    float* out = (float*)d_out;

    float* out_all  = (float*)d_ws;                       // [DN][NN][LL]
    float* last_buf = out_all + (size_t)DN * NN * LL;     // [DN][LL]

    dag_level_kernel<<<DN, BT, 0, stream>>>(atom, pred, W_single, b_single,
                                            W_merge, b_merge, attn_w,
                                            out_all, last_buf);
    final_pool_kernel<<<1, 256, 0, stream>>>(last_buf, dag_w, W_final, b_final, out);
}